// Round 5
// baseline (291.801 us; speedup 1.0000x reference)
//
#include <hip/hip_runtime.h>

// BlockLinearLayer: out[r, n*8+j] = sum_k x[r, n*32+k] * W[n,j,k] + b[n*8+j]
// x: [65536, 4096] f32, W: [128, 8, 32] f32, b: [1024] f32, out: [65536, 1024] f32
//
// Memory-bound: 1.342 GB traffic, floor ~213 us at the 6.29 TB/s copy ceiling.
// Run-length evidence: R1 (16B writes) 413us; R4 (256B/64B runs) 276us;
// R2 (512B/128B runs) 242us. This round: 1KB read runs / 256B write runs.
// Tile = 64 rows x 256 x-cols (8 n-blocks), 512 threads = 8 waves,
// wave w owns n-block w  -> n wave-uniform -> W/bias via s_load broadcast.
// LDS = exactly 64KB: row stride 256 dwords with XOR float4-swizzle
// (c4 ^= row&7) instead of padding -> fits static limit, ds_read/ds_write
// both at the 8-phase minimum. 2 blocks/CU x 8 waves = 16 waves/CU (same
// wave count as R2). Phase-serialized (3 barriers) -- overlap comes from
// cross-block stagger, which the compiler's pre-barrier vmcnt(0) drain
// cannot defeat (R3 lesson).

#define IN_COLS   4096
#define OUT_COLS  1024
#define OS        68        // LDS out-row stride (dwords) = 64 + 4 pad

typedef float f32x4 __attribute__((ext_vector_type(4)));

__global__ __launch_bounds__(512, 4)
void blocklinear_kernel(const float* __restrict__ x,
                        const float* __restrict__ W,
                        const float* __restrict__ bias,
                        float* __restrict__ out)
{
    __shared__ float lds[64 * 256];    // 65536 B exactly; out region overlays
    const int t     = threadIdx.x;
    const int chunk = blockIdx.x;      // 0..15, each = 8 n-blocks (256 x-cols)
    const int r0    = blockIdx.y * 64;

    // ---- stage x tile [64 rows x 256 cols]: 8 iters, 8 rows x 1KB per instr
    {
        const int f  = t & 63;         // float4 col 0..63 (1 KB per row)
        const int rr = t >> 6;         // row-sub 0..7
        const float* xb = x + (size_t)(r0 + rr) * IN_COLS + chunk * 256 + f * 4;
#pragma unroll
        for (int it = 0; it < 8; ++it) {
            const int row = it * 8 + rr;
            f32x4 v = *reinterpret_cast<const f32x4*>(xb + (size_t)it * 8 * IN_COLS);
            // XOR-swizzled float4 slot: breaks the stride-256 bank aliasing
            *reinterpret_cast<f32x4*>(&lds[row * 256 + ((f ^ (row & 7)) * 4)]) = v;
        }
    }
    __syncthreads();

    // ---- compute: wave w owns n-block chunk*8+w, lane l owns row l
    const int w = __builtin_amdgcn_readfirstlane(t >> 6);   // 0..7, uniform
    const int l = t & 63;
    const int n = chunk * 8 + w;
    const float* Wn = W + (size_t)n * 256;

    float xv[32];
#pragma unroll
    for (int q = 0; q < 8; ++q) {
        f32x4 v = *reinterpret_cast<const f32x4*>(
            &lds[l * 256 + (((w * 8 + q) ^ (l & 7)) * 4)]);
        xv[4*q+0] = v.x; xv[4*q+1] = v.y; xv[4*q+2] = v.z; xv[4*q+3] = v.w;
    }

    float acc[8];
#pragma unroll
    for (int j = 0; j < 8; ++j) {
        float s = bias[n * 8 + j];
#pragma unroll
        for (int k = 0; k < 32; ++k)
            s = fmaf(Wn[j * 32 + k], xv[k], s);
        acc[j] = s;
    }
    __syncthreads();   // all x reads done before overlaying LDS with out

    // ---- stage acc to LDS out region [64 rows x 64 cols], stride 68
    {
        f32x4 v0 = { acc[0], acc[1], acc[2], acc[3] };
        f32x4 v1 = { acc[4], acc[5], acc[6], acc[7] };
        reinterpret_cast<f32x4*>(&lds[l * OS + w * 8])[0] = v0;
        reinterpret_cast<f32x4*>(&lds[l * OS + w * 8 + 4])[0] = v1;
    }
    __syncthreads();

    // ---- cooperative store: 2 iters, 32 rows x 256 B runs per instr
    {
        const int of4 = t & 15;        // float4 col 0..15 (256 B per row)
        const int ors = t >> 4;        // row-sub 0..31
#pragma unroll
        for (int m = 0; m < 2; ++m) {
            const int row = m * 32 + ors;
            f32x4 v = *reinterpret_cast<const f32x4*>(&lds[row * OS + of4 * 4]);
            *reinterpret_cast<f32x4*>(
                out + (size_t)(r0 + row) * OUT_COLS + chunk * 64 + of4 * 4) = v;
        }
    }
}

extern "C" void kernel_launch(void* const* d_in, const int* in_sizes, int n_in,
                              void* d_out, int out_size, void* d_ws, size_t ws_size,
                              hipStream_t stream)
{
    const float* x = (const float*)d_in[0];
    const float* W = (const float*)d_in[1];
    const float* b = (const float*)d_in[2];
    float* out = (float*)d_out;

    const int rows = in_sizes[0] / IN_COLS;        // 65536
    dim3 grid(IN_COLS / 256, rows / 64);           // (16, 1024)
    dim3 block(512);
    hipLaunchKernelGGL(blocklinear_kernel, grid, block, 0, stream, x, W, b, out);
}

// Round 7
// 242.436 us; speedup vs baseline: 1.2036x; 1.2036x over previous
//
#include <hip/hip_runtime.h>

// BlockLinearLayer: out[r, n*8+j] = sum_k x[r, n*32+k] * W[n,j,k] + b[n*8+j]
// x: [65536, 4096] f32, W: [128, 8, 32] f32, b: [1024] f32, out: [65536, 1024] f32
//
// Memory-bound: 1.342 GB traffic, floor ~213 us (6.29 TB/s copy ceiling).
// Best passing: R2 = 242 us (64x128 tile, 256 threads, LDS-staged full-line
// runs, wave-uniform W -> s_load, 3-barrier phase-serial, 4 blocks/CU).
// R6 failed on an ldsO stride bug (OS=20 for 32-float rows -> cross-row
// corruption), NOT on global_load_lds (swizzle math verified: slot s of row
// r holds source f4-col s^(r&7) on both sides). This round = R6 fixed:
//   - OS = 36 (32 floats + 4 pad)
//   - ldsO overlays ldsX (R2-style, 3 barriers) -> 32768 B total
//   - __launch_bounds__(256,5): 5 blocks/CU of cross-block phase stagger
//   - global_load_lds staging: no VGPR round-trip, no ds_writes; linear LDS
//     dest + rule-21 swizzle pair (pre-swizzled global SOURCE, XOR on read)

#define IN_COLS   4096
#define OUT_COLS  1024
#define OS        36        // ldsO row stride (dwords) = 32 + 4 pad

typedef float f32x4 __attribute__((ext_vector_type(4)));
typedef __attribute__((address_space(1))) const void gvoid;
typedef __attribute__((address_space(3))) void lvoid;

__global__ __launch_bounds__(256, 5)
void blocklinear_kernel(const float* __restrict__ x,
                        const float* __restrict__ W,
                        const float* __restrict__ bias,
                        float* __restrict__ out)
{
    __shared__ float ldsX[64 * 128];   // 32768 B, linear (gload_lds dest);
    float* ldsO = ldsX;                // out region overlays after barrier 2
    const int t     = threadIdx.x;
    const int chunk = blockIdx.x;      // 0..31, 4 n-blocks (128 x-cols) each
    const int r0    = blockIdx.y * 64;

    const int w = __builtin_amdgcn_readfirstlane(t >> 6);  // wave 0..3
    const int l = t & 63;

    // ---- stage x tile [64 rows x 128 cols] via global_load_lds.
    // Wave w fills rows [w*16, w*16+16): 8 instrs x 1 KB (2 rows each).
    // LDS dest linear (wave-uniform base + lane*16); bank swizzle lives on
    // the SOURCE: lane fetches f4-col (l&31)^(row&7) so that LDS slot s of
    // row r holds source f4-col s^(r&7).
    {
        const int rsub = l >> 5;                 // 0/1: row within the pair
#pragma unroll
        for (int it = 0; it < 8; ++it) {
            const int row = w * 16 + it * 2 + rsub;
            const int sc  = (l & 31) ^ (row & 7);        // swizzled source f4
            const float* src = x + (size_t)(r0 + row) * IN_COLS
                                 + chunk * 128 + sc * 4;
            float* dst = &ldsX[(w * 16 + it * 2) * 128]; // wave-uniform base
            __builtin_amdgcn_global_load_lds((gvoid*)src, (lvoid*)dst, 16, 0, 0);
        }
    }
    __syncthreads();   // vmcnt(0) drain + barrier: tile resident

    // ---- compute: wave w owns n-block chunk*4+w, lane l owns row l
    const int n = chunk * 4 + w;
    const float* Wn = W + (size_t)n * 256;

    float xv[32];
#pragma unroll
    for (int q = 0; q < 8; ++q) {
        const int s = (w * 8 + q) ^ (l & 7);     // un-swizzle on read
        f32x4 v = *reinterpret_cast<const f32x4*>(&ldsX[l * 128 + s * 4]);
        xv[4*q+0] = v.x; xv[4*q+1] = v.y; xv[4*q+2] = v.z; xv[4*q+3] = v.w;
    }

    float acc[8];
#pragma unroll
    for (int j = 0; j < 8; ++j) {
        float s = bias[n * 8 + j];
#pragma unroll
        for (int k = 0; k < 32; ++k)
            s = fmaf(Wn[j * 32 + k], xv[k], s);
        acc[j] = s;
    }
    __syncthreads();   // all ldsX reads done before overlaying with out

    // ---- stage acc to LDS out region [64 rows x 32 cols], stride 36
    {
        f32x4 v0 = { acc[0], acc[1], acc[2], acc[3] };
        f32x4 v1 = { acc[4], acc[5], acc[6], acc[7] };
        reinterpret_cast<f32x4*>(&ldsO[l * OS + w * 8])[0] = v0;
        reinterpret_cast<f32x4*>(&ldsO[l * OS + w * 8 + 4])[0] = v1;
    }
    __syncthreads();

    // ---- cooperative store: 2 iters, 32 rows x 128 B contiguous runs
    {
        const int of4 = t & 7;          // f4 col 0..7 (128 B per row)
        const int ors = t >> 3;         // row-sub 0..31
#pragma unroll
        for (int m = 0; m < 2; ++m) {
            const int row = m * 32 + ors;
            f32x4 v = *reinterpret_cast<const f32x4*>(&ldsO[row * OS + of4 * 4]);
            *reinterpret_cast<f32x4*>(
                out + (size_t)(r0 + row) * OUT_COLS + chunk * 32 + of4 * 4) = v;
        }
    }
}

extern "C" void kernel_launch(void* const* d_in, const int* in_sizes, int n_in,
                              void* d_out, int out_size, void* d_ws, size_t ws_size,
                              hipStream_t stream)
{
    const float* x = (const float*)d_in[0];
    const float* W = (const float*)d_in[1];
    const float* b = (const float*)d_in[2];
    float* out = (float*)d_out;

    const int rows = in_sizes[0] / IN_COLS;        // 65536
    dim3 grid(IN_COLS / 128, rows / 64);           // (32, 1024)
    dim3 block(256);
    hipLaunchKernelGGL(blocklinear_kernel, grid, block, 0, stream, x, W, b, out);
}